// Round 7
// baseline (262.098 us; speedup 1.0000x reference)
//
#include <hip/hip_runtime.h>
#include <math.h>

typedef __bf16 bf16_t;
typedef __bf16 bf16x8 __attribute__((ext_vector_type(8)));
typedef float f32x4 __attribute__((ext_vector_type(4)));

#define GLOAD_LDS16(g, l)                                                      \
  __builtin_amdgcn_global_load_lds(                                            \
      (const __attribute__((address_space(1))) void*)(g),                      \
      (__attribute__((address_space(3))) void*)(l), 16, 0, 0)

// ---------------------------------------------------------------------------
// Prep: build bf16 operands.
// ---------------------------------------------------------------------------
__global__ __launch_bounds__(256) void prep_kernel(
    const float* __restrict__ enc, const float* __restrict__ dec,
    const float* __restrict__ ot, const float* __restrict__ W_enc,
    const float* __restrict__ W_ot, const float* __restrict__ W_dec,
    const float* __restrict__ W_out, bf16_t* __restrict__ Acat,
    bf16_t* __restrict__ Dec, bf16_t* __restrict__ WcatT,
    bf16_t* __restrict__ WdecT, bf16_t* __restrict__ WoutT) {
  int idx = blockIdx.x * 256 + threadIdx.x;
  const int N0 = 1600 * 1024, N1 = 400 * 512, N2 = 640 * 1024, N3 = 640 * 512,
            N4 = 1024 * 640;
  if (idx < N0) {
    int r = idx >> 10, c = idx & 1023;
    float v = (c < 512) ? enc[(r << 9) + c] : ot[(r << 9) + (c - 512)];
    Acat[idx] = (bf16_t)v;
    return;
  }
  idx -= N0;
  if (idx < N1) {
    Dec[idx] = (bf16_t)dec[idx];
    return;
  }
  idx -= N1;
  if (idx < N2) {
    int f = idx >> 10, k = idx & 1023;
    float v = (k < 512) ? W_enc[k * 640 + f] : W_ot[(k - 512) * 640 + f];
    WcatT[idx] = (bf16_t)v;
    return;
  }
  idx -= N2;
  if (idx < N3) {
    int f = idx >> 9, k = idx & 511;
    WdecT[idx] = (bf16_t)W_dec[k * 640 + f];
    return;
  }
  idx -= N3;
  if (idx < N4) {
    int v = idx / 640, f = idx - v * 640;
    WoutT[idx] = (bf16_t)W_out[f * 1024 + v];
    return;
  }
}

// ---------------------------------------------------------------------------
// Stage 1: out[M][640] = tanh(A[M][K] @ Bt[640][K]^T + bias1 (+ bias2))
// ---------------------------------------------------------------------------
__global__ __launch_bounds__(256) void gemm_tanh_kernel(
    const bf16_t* __restrict__ A, const bf16_t* __restrict__ Bt,
    const float* __restrict__ bias1, const float* __restrict__ bias2,
    float* __restrict__ out, int M, int K) {
  __shared__ bf16_t As[64 * 32];
  __shared__ bf16_t Bs[64 * 32];
  const int tid = threadIdx.x;
  const int wid = tid >> 6, lane = tid & 63;
  const int wm = wid >> 1, wn = wid & 1;
  const int r0 = blockIdx.y * 64, n0 = blockIdx.x * 64;

  const int ia = wid * 16 + (lane >> 2);
  const int sa = lane & 3;
  int ra = r0 + ia;
  if (ra > M - 1) ra = M - 1;
  const bf16_t* gA = A + (size_t)ra * K + sa * 8;
  const bf16_t* gB = Bt + (size_t)(n0 + ia) * K + sa * 8;
  bf16_t* lA = As + wid * 512;
  bf16_t* lB = Bs + wid * 512;

  f32x4 acc[2][2] = {};
  const int lr = lane & 15, kg = lane >> 4;
  const int steps = K >> 5;
  for (int ks = 0; ks < steps; ++ks) {
    GLOAD_LDS16(gA + ks * 32, lA);
    GLOAD_LDS16(gB + ks * 32, lB);
    __syncthreads();
    bf16x8 af[2], bfr[2];
#pragma unroll
    for (int a = 0; a < 2; ++a)
      af[a] = *(const bf16x8*)(As + (wm * 32 + a * 16 + lr) * 32 + kg * 8);
#pragma unroll
    for (int b = 0; b < 2; ++b)
      bfr[b] = *(const bf16x8*)(Bs + (wn * 32 + b * 16 + lr) * 32 + kg * 8);
#pragma unroll
    for (int a = 0; a < 2; ++a)
#pragma unroll
      for (int b = 0; b < 2; ++b)
        acc[a][b] =
            __builtin_amdgcn_mfma_f32_16x16x32_bf16(af[a], bfr[b], acc[a][b], 0, 0, 0);
    __syncthreads();
  }
#pragma unroll
  for (int a = 0; a < 2; ++a)
#pragma unroll
    for (int b = 0; b < 2; ++b) {
      int col = n0 + wn * 32 + b * 16 + lr;
      float bv = bias1[col] + (bias2 ? bias2[col] : 0.0f);
#pragma unroll
      for (int j = 0; j < 4; ++j) {
        int rg = r0 + wm * 32 + a * 16 + kg * 4 + j;
        if (rg < M) out[(size_t)rg * 640 + col] = tanhf(acc[a][b][j] + bv);
      }
    }
}

// ---------------------------------------------------------------------------
// Materialize joint A: Amat[80128][640] bf16 = tanh(fused+proj_dec) via the
// tanh addition identity. Pad rows zeroed.
// ---------------------------------------------------------------------------
__global__ __launch_bounds__(256) void materialize_joint_kernel(
    const float* __restrict__ ta,   // [1600][640]
    const float* __restrict__ tb,   // [400][640]
    bf16_t* __restrict__ Amat) {    // [80128][640]
  const int idx = blockIdx.x * 256 + threadIdx.x;  // 0 .. 80128*80-1
  const int row = idx / 80;
  const int s = idx - row * 80;
  bf16x8 jv;
  if (row >= 80000) {
#pragma unroll
    for (int e = 0; e < 8; ++e) jv[e] = (bf16_t)0.0f;
    *(bf16x8*)(Amat + (size_t)row * 640 + s * 8) = jv;
    return;
  }
  const int frow = row / 50;          // b*T + t
  const int bidx = row / 10000;       // b
  const int u = row - frow * 50;      // u
  const float* taP = ta + (size_t)frow * 640 + s * 8;
  const float* tbP = tb + (size_t)(bidx * 50 + u) * 640 + s * 8;
#pragma unroll
  for (int h = 0; h < 2; ++h) {
    f32x4 xa = *(const f32x4*)(taP + h * 4);
    f32x4 xb = *(const f32x4*)(tbP + h * 4);
#pragma unroll
    for (int e = 0; e < 4; ++e) {
      float d = fmaxf(1.0f + xa[e] * xb[e], 1e-6f);
      jv[h * 4 + e] = (bf16_t)((xa[e] + xb[e]) * __builtin_amdgcn_rcpf(d));
    }
  }
  *(bf16x8*)(Amat + (size_t)row * 640 + s * 8) = jv;
}

// ---------------------------------------------------------------------------
// Stage 2: fine-interleaved phase-scheduled GEMM (m196/m201-faithful port).
//  out[80000][1024] = Amat[80128][640] @ WoutT[1024][640]^T + b_out
//  256x256 tile, 512 thr, 8 waves 2(M)x4(N), wave tile 128x64 of 16x16x32.
//  BK=32 -> 20 K-tiles; 2 phases/K-tile, each {ds-reads | 2 gload_lds |
//  B1 | lgkm(0)+schedbar | setprio 16 MFMA | B2}; counted vmcnt(4) ONCE
//  per K-tile (end of P1). 4-slot LDS ring (128 KiB), prefetch distance 2.
//  Staging: each wave stages ONLY the quarters it reads (A-half wm,
//  B-half wn>>1) -> per-wave vmcnt + barrier => residency (ledger-verified).
//  Swizzle (both sides): read slot = kg ^ ((row>>1)&3); gload source col
//  pre-permuted by (l&3)^((l>>3)&3) (constant, since row-bases 16-aligned).
// ---------------------------------------------------------------------------
__global__ __launch_bounds__(512, 1) void joint_gemm8_kernel(
    const bf16_t* __restrict__ Amat,   // [80128][640]
    const bf16_t* __restrict__ WoutT,  // [1024][640]
    const float* __restrict__ b_out,   // [1024]
    float* __restrict__ out) {         // [80000][1024]
  __shared__ __align__(16) unsigned char L[131072];  // 4 slots x (A16K|B16K)
  const int tid = threadIdx.x;
  const int wid = tid >> 6, l = tid & 63;
  const int wm = wid >> 2, wn = wid & 3;

  // bijective XCD swizzle (m204): nwg=1252, q=156, r=4; 4 N-siblings adjacent.
  const int orig = blockIdx.x;
  const int xcd = orig & 7, lid = orig >> 3;
  const int wg = (xcd < 4 ? xcd * 157 : 4 * 157 + (xcd - 4) * 156) + lid;
  const int mb = wg >> 2, nb = wg & 3;
  const int r0 = mb * 256, n0 = nb * 256;

  // ---- staging sources (per-lane, col pre-permuted for swizzle) ----
  const int srow = l >> 2;
  const int perm = ((l & 3) ^ ((l >> 3) & 3)) * 8;  // element offset
  const bf16_t* gA =
      Amat + (size_t)(r0 + wm * 128 + wn * 32 + srow) * 640 + perm;
  const bf16_t* gB =
      WoutT +
      (size_t)(n0 + (wn >> 1) * 128 + ((wn & 1) * 2 + wm) * 32 + srow) * 640 +
      perm;
  // wave-uniform LDS dest byte offsets within a slot (HW adds lane*16)
  const int dA = wm * 8192 + wn * 2048;
  const int dB = 16384 + (wn >> 1) * 8192 + ((wn & 1) * 2 + wm) * 2048;

  // ---- frag read byte offsets (sans slot base) ----
  int aoff[8], boff[4];
#pragma unroll
  for (int mf = 0; mf < 8; ++mf) {
    int rr = mf * 16 + (l & 15);
    aoff[mf] = wm * 8192 + rr * 64 + (((l >> 4) ^ ((rr >> 1) & 3)) * 16);
  }
#pragma unroll
  for (int nf = 0; nf < 4; ++nf) {
    int rr = (wn & 1) * 64 + nf * 16 + (l & 15);
    boff[nf] =
        16384 + (wn >> 1) * 8192 + rr * 64 + (((l >> 4) ^ ((rr >> 1) & 3)) * 16);
  }

  f32x4 acc[8][4] = {};

  // ---- prologue: stage K-tiles 0 (slot0) and 1 (slot1) ----
#pragma unroll
  for (int t = 0; t < 2; ++t) {
    const unsigned sb = t * 32768u;
    GLOAD_LDS16(gA + t * 32, L + sb + dA);
    GLOAD_LDS16(gA + t * 32 + 16 * 640, L + sb + dA + 1024);
    GLOAD_LDS16(gB + t * 32, L + sb + dB);
    GLOAD_LDS16(gB + t * 32 + 16 * 640, L + sb + dB + 1024);
  }
  asm volatile("s_waitcnt vmcnt(4)" ::: "memory");  // tile0 resident
  __builtin_amdgcn_s_barrier();

#pragma unroll 1
  for (int t = 0; t < 20; ++t) {
    const unsigned sb = (unsigned)(t & 3) * 32768u;
    const unsigned pb = (unsigned)((t + 2) & 3) * 32768u;
    const size_t ko = (size_t)(t + 2) * 32;
    bf16x8 af[4], bf[4];

    // ======== P0: read A0-3,B0-3 | stage A(t+2) | sync | MFMA mf0-3 ========
#pragma unroll
    for (int mf = 0; mf < 4; ++mf)
      af[mf] = *(const bf16x8*)(L + sb + aoff[mf]);
#pragma unroll
    for (int nf = 0; nf < 4; ++nf)
      bf[nf] = *(const bf16x8*)(L + sb + boff[nf]);
    if (t < 18) {
      GLOAD_LDS16(gA + ko, L + pb + dA);
      GLOAD_LDS16(gA + ko + 16 * 640, L + pb + dA + 1024);
    }
    __builtin_amdgcn_sched_barrier(0);
    __builtin_amdgcn_s_barrier();
    asm volatile("s_waitcnt lgkmcnt(0)" ::: "memory");
    __builtin_amdgcn_sched_barrier(0);
    __builtin_amdgcn_s_setprio(1);
#pragma unroll
    for (int mf = 0; mf < 4; ++mf)
#pragma unroll
      for (int nf = 0; nf < 4; ++nf)
        acc[mf][nf] = __builtin_amdgcn_mfma_f32_16x16x32_bf16(
            af[mf], bf[nf], acc[mf][nf], 0, 0, 0);
    __builtin_amdgcn_s_setprio(0);
    __builtin_amdgcn_sched_barrier(0);
    __builtin_amdgcn_s_barrier();

    // ======== P1: read A4-7 | stage B(t+2) | sync | MFMA mf4-7 | vmcnt ======
#pragma unroll
    for (int mf = 0; mf < 4; ++mf)
      af[mf] = *(const bf16x8*)(L + sb + aoff[4 + mf]);
    if (t < 18) {
      GLOAD_LDS16(gB + ko, L + pb + dB);
      GLOAD_LDS16(gB + ko + 16 * 640, L + pb + dB + 1024);
    }
    __builtin_amdgcn_sched_barrier(0);
    __builtin_amdgcn_s_barrier();
    asm volatile("s_waitcnt lgkmcnt(0)" ::: "memory");
    __builtin_amdgcn_sched_barrier(0);
    __builtin_amdgcn_s_setprio(1);
#pragma unroll
    for (int mf = 0; mf < 4; ++mf)
#pragma unroll
      for (int nf = 0; nf < 4; ++nf)
        acc[4 + mf][nf] = __builtin_amdgcn_mfma_f32_16x16x32_bf16(
            af[mf], bf[nf], acc[4 + mf][nf], 0, 0, 0);
    __builtin_amdgcn_s_setprio(0);
    if (t < 18) {
      asm volatile("s_waitcnt vmcnt(4)" ::: "memory");  // t+1 fully resident
    } else {
      asm volatile("s_waitcnt vmcnt(0)" ::: "memory");  // tail drain
    }
    __builtin_amdgcn_sched_barrier(0);
    __builtin_amdgcn_s_barrier();
  }

  // ---- epilogue: + b_out, store f32 (16x16 C/D: col=l&15, row=kg*4+j) ----
  const int kg = l >> 4;
#pragma unroll
  for (int nf = 0; nf < 4; ++nf) {
    const int col = n0 + wn * 64 + nf * 16 + (l & 15);
    const float bv = b_out[col];
#pragma unroll
    for (int mf = 0; mf < 8; ++mf) {
      const int rg = r0 + wm * 128 + mf * 16 + kg * 4;
      float* op = out + (size_t)rg * 1024 + col;
      const f32x4 v = acc[mf][nf];
#pragma unroll
      for (int j = 0; j < 4; ++j)
        if (rg + j < 80000) op[(size_t)j * 1024] = v[j] + bv;
    }
  }
}

// ---------------------------------------------------------------------------
extern "C" void kernel_launch(void* const* d_in, const int* in_sizes, int n_in,
                              void* d_out, int out_size, void* d_ws,
                              size_t ws_size, hipStream_t stream) {
  const float* enc = (const float*)d_in[0];
  const float* dec = (const float*)d_in[1];
  const float* ot = (const float*)d_in[2];
  const float* W_enc = (const float*)d_in[3];
  const float* b_enc = (const float*)d_in[4];
  const float* W_ot = (const float*)d_in[5];
  const float* b_ot = (const float*)d_in[6];
  const float* W_dec = (const float*)d_in[7];
  const float* b_dec = (const float*)d_in[8];
  const float* W_out = (const float*)d_in[9];
  const float* b_out = (const float*)d_in[10];
  float* out = (float*)d_out;

  char* ws = (char*)d_ws;
  size_t off = 0;
  auto alloc = [&](size_t bytes) {
    void* p = ws + off;
    off += (bytes + 255) & ~(size_t)255;
    return p;
  };
  float* ta = (float*)alloc(1600 * 640 * 4);        // tanh(fused)
  float* tb = (float*)alloc(400 * 640 * 4);         // tanh(proj_dec)
  bf16_t* Acat = (bf16_t*)alloc(1600 * 1024 * 2);
  bf16_t* Dec = (bf16_t*)alloc(400 * 512 * 2);
  bf16_t* WcatT = (bf16_t*)alloc(640 * 1024 * 2);
  bf16_t* WdecT = (bf16_t*)alloc(640 * 512 * 2);
  bf16_t* WoutT = (bf16_t*)alloc(1024 * 640 * 2);
  bf16_t* Amat = (bf16_t*)alloc((size_t)80128 * 640 * 2);  // joint bf16

  prep_kernel<<<13600, 256, 0, stream>>>(enc, dec, ot, W_enc, W_ot, W_dec,
                                         W_out, Acat, Dec, WcatT, WdecT, WoutT);
  gemm_tanh_kernel<<<dim3(10, 25), 256, 0, stream>>>(Acat, WcatT, b_enc, b_ot,
                                                     ta, 1600, 1024);
  gemm_tanh_kernel<<<dim3(10, 7), 256, 0, stream>>>(Dec, WdecT, b_dec, nullptr,
                                                    tb, 400, 512);
  materialize_joint_kernel<<<25040, 256, 0, stream>>>(ta, tb, Amat);
  joint_gemm8_kernel<<<1252, 512, 0, stream>>>(Amat, WoutT, b_out, out);
}